// Round 1
// baseline (455.251 us; speedup 1.0000x reference)
//
#include <hip/hip_runtime.h>

#define NDIM 256
#define NN (NDIM*NDIM)

typedef __attribute__((ext_vector_type(8))) short s8bf;    // 8 x bf16 (4 VGPRs)
typedef __attribute__((ext_vector_type(4))) float f32x4;   // MFMA accum

__device__ __forceinline__ unsigned short f2bf(float f) {
    union { float f; unsigned u; } v; v.f = f;
    unsigned u = v.u;
    return (unsigned short)((u + 0x7FFFu + ((u >> 16) & 1u)) >> 16);  // RNE
}

// ---------------- expm pipeline (tiny 256x256 complex) ----------------

// Mr = H[1], Mi = -H[0]   (M = H1 - i*H0 = -i*(H0 + i*H1))
__global__ void k_build(const float* __restrict__ H, float* __restrict__ Mr,
                        float* __restrict__ Mi) {
    int i = blockIdx.x * blockDim.x + threadIdx.x;
    Mr[i] = H[NN + i];
    Mi[i] = -H[i];
}

// C = A*B (+ D), all 256x256 complex as separate r/i planes
__global__ __launch_bounds__(256) void cmatmul(
    const float* __restrict__ Ar, const float* __restrict__ Ai,
    const float* __restrict__ Br, const float* __restrict__ Bi,
    const float* __restrict__ Dr, const float* __restrict__ Di,
    float* __restrict__ Cr, float* __restrict__ Ci, int hasD) {
    __shared__ float Asr[16][17], Asi[16][17], Bsr[16][17], Bsi[16][17];
    const int tx = threadIdx.x, ty = threadIdx.y;
    const int row = blockIdx.y * 16 + ty, col = blockIdx.x * 16 + tx;
    float sr = 0.f, si = 0.f;
    for (int kk = 0; kk < NDIM; kk += 16) {
        Asr[ty][tx] = Ar[row * NDIM + kk + tx];
        Asi[ty][tx] = Ai[row * NDIM + kk + tx];
        Bsr[ty][tx] = Br[(kk + ty) * NDIM + col];
        Bsi[ty][tx] = Bi[(kk + ty) * NDIM + col];
        __syncthreads();
#pragma unroll
        for (int k = 0; k < 16; ++k) {
            float ar = Asr[ty][k], ai = Asi[ty][k];
            float br = Bsr[k][tx], bi = Bsi[k][tx];
            sr = fmaf(ar, br, sr); sr = fmaf(-ai, bi, sr);
            si = fmaf(ar, bi, si); si = fmaf(ai, br, si);
        }
        __syncthreads();
    }
    int o = row * NDIM + col;
    if (hasD) { sr += Dr[o]; si += Di[o]; }
    Cr[o] = sr; Ci[o] = si;
}

// B0 = I + M + M^2/2 ; B1 = I/6 + M/24 + M^2/120 ; B2 = I/720 + M/5040 + M^2/40320
__global__ void k_bmats(const float* __restrict__ Mr, const float* __restrict__ Mi,
                        const float* __restrict__ M2r, const float* __restrict__ M2i,
                        float* B0r, float* B0i, float* B1r, float* B1i,
                        float* B2r, float* B2i) {
    int i = blockIdx.x * blockDim.x + threadIdx.x;
    float di = (i % 257 == 0) ? 1.f : 0.f;   // i = r*256+c, diag iff 257 | i
    float mr = Mr[i], mi = Mi[i], m2r = M2r[i], m2i = M2i[i];
    B0r[i] = di + mr + 0.5f * m2r;
    B0i[i] = mi + 0.5f * m2i;
    B1r[i] = di * (1.f/6.f)   + mr * (1.f/24.f)   + m2r * (1.f/120.f);
    B1i[i] =                    mi * (1.f/24.f)   + m2i * (1.f/120.f);
    B2r[i] = di * (1.f/720.f) + mr * (1.f/5040.f) + m2r * (1.f/40320.f);
    B2i[i] =                    mi * (1.f/5040.f) + m2i * (1.f/40320.f);
}

// Ut[e*256+d] = bf16(Rr[d*256+e])   (transposed real part -> B^T for the GEMM)
__global__ void k_transpose(const float* __restrict__ Rr, unsigned short* __restrict__ Ut) {
    int i = blockIdx.x * blockDim.x + threadIdx.x;
    int e = i >> 8, d = i & 255;
    Ut[i] = f2bf(Rr[d * NDIM + e]);
}

// ---------------- main GEMM: out[131072 x 256] = psi @ Ur ----------------
// 1024 threads (16 waves), each wave owns a 16-row strip; full Ut (bf16,
// 128 KB) staged in LDS with XOR swizzle; 2 strips per wave (512 rows/block).
__global__ __launch_bounds__(1024, 4) void kgemm(
    const float* __restrict__ psi, const unsigned short* __restrict__ Ut,
    float* __restrict__ out) {
    __shared__ unsigned short Uls[NN];   // 128 KB
    const int t = threadIdx.x;

    // stage global->LDS (8192 x 16B groups), swizzled: slot gi ^= (e & 7)
    const s8bf* Ug = (const s8bf*)Ut;
    s8bf* Ls = (s8bf*)Uls;
#pragma unroll
    for (int i = 0; i < 8; ++i) {
        int g = t + i * 1024;
        int e = g >> 5, gi = g & 31;
        Ls[(e << 5) | (gi ^ (e & 7))] = Ug[g];
    }
    __syncthreads();

    const int w = t >> 6, lane = t & 63;
    const int c = lane & 15, q = lane >> 4;

    for (int it = 0; it < 2; ++it) {
        const int r0 = blockIdx.x * 512 + it * 256 + w * 16;
        const float* prow = psi + (r0 + c) * NDIM;
        f32x4 acc[16];
#pragma unroll
        for (int i = 0; i < 16; ++i) acc[i] = (f32x4)0.0f;

#pragma unroll
        for (int s = 0; s < 8; ++s) {
            const int k0 = s * 32 + q * 8;
            float4 a0 = *(const float4*)(prow + k0);
            float4 a1 = *(const float4*)(prow + k0 + 4);
            s8bf af;
            af[0] = (short)f2bf(a0.x); af[1] = (short)f2bf(a0.y);
            af[2] = (short)f2bf(a0.z); af[3] = (short)f2bf(a0.w);
            af[4] = (short)f2bf(a1.x); af[5] = (short)f2bf(a1.y);
            af[6] = (short)f2bf(a1.z); af[7] = (short)f2bf(a1.w);
            const int gi = s * 4 + q;
#pragma unroll
            for (int ct = 0; ct < 16; ++ct) {
                int e = ct * 16 + c;
                s8bf bf = Ls[(e << 5) | (gi ^ (e & 7))];
                acc[ct] = __builtin_amdgcn_mfma_f32_16x16x32_bf16(af, bf, acc[ct], 0, 0, 0);
            }
        }
        // C/D layout: col = lane&15, row = (lane>>4)*4 + reg  [m89]
        float* orow = out + (r0 + q * 4) * NDIM + c;
#pragma unroll
        for (int ct = 0; ct < 16; ++ct) {
#pragma unroll
            for (int r = 0; r < 4; ++r) orow[r * NDIM + ct * 16] = acc[ct][r];
        }
    }
}

extern "C" void kernel_launch(void* const* d_in, const int* in_sizes, int n_in,
                              void* d_out, int out_size, void* d_ws, size_t ws_size,
                              hipStream_t stream) {
    const float* psi = (const float*)d_in[0];   // [8,4096,4,256] f32
    const float* H   = (const float*)d_in[1];   // [4,256,256]    f32
    float* out = (float*)d_out;                 // [8,4096,4,256] f32

    float* w = (float*)d_ws;                    // needs ~4.2 MB
    float *Mr  = w + 0*NN,  *Mi  = w + 1*NN;
    float *M2r = w + 2*NN,  *M2i = w + 3*NN;
    float *M3r = w + 4*NN,  *M3i = w + 5*NN;
    float *B0r = w + 6*NN,  *B0i = w + 7*NN;
    float *B1r = w + 8*NN,  *B1i = w + 9*NN;
    float *B2r = w + 10*NN, *B2i = w + 11*NN;
    float *R1r = w + 12*NN, *R1i = w + 13*NN;
    float *Rr  = w + 14*NN, *Ri  = w + 15*NN;
    unsigned short* Ut = (unsigned short*)(w + 16*NN);

    dim3 cb(16, 16), cg(16, 16);
    k_build<<<NN / 256, 256, 0, stream>>>(H, Mr, Mi);
    cmatmul<<<cg, cb, 0, stream>>>(Mr, Mi, Mr, Mi, nullptr, nullptr, M2r, M2i, 0);
    cmatmul<<<cg, cb, 0, stream>>>(M2r, M2i, Mr, Mi, nullptr, nullptr, M3r, M3i, 0);
    k_bmats<<<NN / 256, 256, 0, stream>>>(Mr, Mi, M2r, M2i, B0r, B0i, B1r, B1i, B2r, B2i);
    cmatmul<<<cg, cb, 0, stream>>>(M3r, M3i, B2r, B2i, B1r, B1i, R1r, R1i, 1);  // R1 = M3*B2 + B1
    cmatmul<<<cg, cb, 0, stream>>>(M3r, M3i, R1r, R1i, B0r, B0i, Rr, Ri, 1);    // U  = M3*R1 + B0
    k_transpose<<<NN / 256, 256, 0, stream>>>(Rr, Ut);
    kgemm<<<256, 1024, 0, stream>>>(psi, Ut, out);
}

// Round 3
// 197.920 us; speedup vs baseline: 2.3002x; 2.3002x over previous
//
#include <hip/hip_runtime.h>

#define NDIM 256
#define NN (NDIM*NDIM)

typedef __attribute__((ext_vector_type(8))) short s8bf;    // 8 x bf16 (4 VGPRs)
typedef __attribute__((ext_vector_type(4))) float f32x4;   // MFMA accum / native float4
typedef __attribute__((ext_vector_type(4))) short s4bf;    // 4 x bf16

__device__ __forceinline__ unsigned short f2bf(float f) {
    union { float f; unsigned u; } v; v.f = f;
    unsigned u = v.u;
    return (unsigned short)((u + 0x7FFFu + ((u >> 16) & 1u)) >> 16);  // RNE
}

// ---------------- expm pipeline: U = B0 + M3*(B1 + M3/720) ----------------
// M = H1 - i*H0. deg-6 Taylor via even/odd PS split; truncation ~1e-4 << bf16 noise.
// mode 0: M2 = M*M        (A=B=M from H)
// mode 1: M3 = M2*M
// mode 2: Ut = bf16( Re( M3*(B1 + M3/720) + B0 ) )^T,  B0=I+M+M2/2, B1=I/6+M/24+M2/120
__global__ __launch_bounds__(256) void kmm(
    const float* __restrict__ H, float2* __restrict__ M2c, float2* __restrict__ M3c,
    unsigned short* __restrict__ Ut, int mode) {
    __shared__ float2 As[16][257];
    __shared__ float2 Bs[256][17];
    const int tx = threadIdx.x, ty = threadIdx.y;
    const int tid = ty * 16 + tx;
    const int r0 = blockIdx.y * 16, c0 = blockIdx.x * 16;

    for (int i = 0; i < 16; ++i) {               // A panel: 16 rows x 256 k
        int idx = i * 256 + tid;
        int r = idx >> 8, k = idx & 255;
        float2 a;
        if (mode == 0)      { a.x = H[NN + (r0+r)*NDIM + k]; a.y = -H[(r0+r)*NDIM + k]; }
        else if (mode == 1) a = M2c[(r0+r)*NDIM + k];
        else                a = M3c[(r0+r)*NDIM + k];
        As[r][k] = a;
    }
    for (int i = 0; i < 16; ++i) {               // B panel: 256 k x 16 cols
        int idx = i * 256 + tid;
        int k = idx >> 4, cc = idx & 15;
        float2 b;
        if (mode <= 1) { b.x = H[NN + k*NDIM + c0+cc]; b.y = -H[k*NDIM + c0+cc]; }
        else {
            int g = k * NDIM + c0 + cc;
            float mr = H[NN + g], mi = -H[g];
            float2 m2 = M2c[g], m3 = M3c[g];
            float di = (k == c0 + cc) ? 1.f : 0.f;
            b.x = di*(1.f/6.f) + mr*(1.f/24.f) + m2.x*(1.f/120.f) + m3.x*(1.f/720.f);
            b.y =                mi*(1.f/24.f) + m2.y*(1.f/120.f) + m3.y*(1.f/720.f);
        }
        Bs[k][cc] = b;
    }
    __syncthreads();

    float sr = 0.f, si = 0.f;
#pragma unroll 8
    for (int k = 0; k < NDIM; ++k) {
        float2 a = As[ty][k], b = Bs[k][tx];
        sr = fmaf(a.x, b.x, sr); sr = fmaf(-a.y, b.y, sr);
        si = fmaf(a.x, b.y, si); si = fmaf(a.y, b.x, si);
    }
    int d = r0 + ty, e = c0 + tx;
    if (mode == 0)      M2c[d*NDIM + e] = make_float2(sr, si);
    else if (mode == 1) M3c[d*NDIM + e] = make_float2(sr, si);
    else {
        int g = d * NDIM + e;
        float ur = sr + ((d == e) ? 1.f : 0.f) + H[NN + g] + M2c[g].x * 0.5f;
        Ut[e * NDIM + d] = f2bf(ur);             // transposed: Ut[col][k]
    }
}

// ---------------- main GEMM: out[131072 x 256] = psi @ Re(U) ----------------
// 512 thr (8 waves) / 128 rows per block / grid 1024. A (psi) staged bf16 in
// swizzled LDS via fully-coalesced NT loads; B-frags straight from global Ut
// (128 KB, L1/L2-hot; s-outer keeps the 16 KB k-slab L1-resident). Epilogue
// transposes acc through wave-private LDS -> NT dwordx4 stores, 1 KB/instr.
__global__ __launch_bounds__(512, 4) void kgemm(
    const float* __restrict__ psi, const unsigned short* __restrict__ Ut,
    float* __restrict__ out) {
    __shared__ unsigned short Als[128 * 256];    // 64 KB bf16, swizzled
    const int t = threadIdx.x;
    const size_t row0 = (size_t)blockIdx.x * 128;

    // ---- stage psi -> LDS: instr i+wave covers one full 1 KB row ----
    const f32x4* psi4 = (const f32x4*)psi;
#pragma unroll
    for (int i = 0; i < 16; ++i) {
        int f = i * 512 + t;                     // float4 index in [0, 8192)
        int r = f >> 6, p = f & 63;              // row, float4-in-row
        f32x4 v = __builtin_nontemporal_load(&psi4[(row0 + r) * 64 + p]);
        s4bf sv;
        sv[0] = (short)f2bf(v[0]); sv[1] = (short)f2bf(v[1]);
        sv[2] = (short)f2bf(v[2]); sv[3] = (short)f2bf(v[3]);
        int slot = p >> 1, half = p & 1;         // 16B slot (8 bf16), 8B half
        int a = r * 256 + ((slot ^ (r & 7)) << 3) + (half << 2);  // ushort units
        *(s4bf*)(&Als[a]) = sv;
    }
    __syncthreads();

    const int w = t >> 6, lane = t & 63;
    const int c = lane & 15, q = lane >> 4;
    const int ar = w * 16 + c;                   // this lane's psi row (A-frag)

    f32x4 acc[16];
#pragma unroll
    for (int i = 0; i < 16; ++i) acc[i] = (f32x4)0.f;

#pragma unroll
    for (int s = 0; s < 8; ++s) {
        // A-frag: k = s*32 + q*8 + j  (slot = s*4+q, swizzled)
        s8bf a = *(const s8bf*)(&Als[ar * 256 + (((s*4 + q) ^ (ar & 7)) << 3)]);
        s8bf bb[8];
#pragma unroll
        for (int j = 0; j < 8; ++j)
            bb[j] = *(const s8bf*)(&Ut[(j*16 + c) * NDIM + s*32 + q*8]);
#pragma unroll
        for (int j = 0; j < 8; ++j)
            acc[j] = __builtin_amdgcn_mfma_f32_16x16x32_bf16(a, bb[j], acc[j], 0, 0, 0);
#pragma unroll
        for (int j = 0; j < 8; ++j)
            bb[j] = *(const s8bf*)(&Ut[((j+8)*16 + c) * NDIM + s*32 + q*8]);
#pragma unroll
        for (int j = 0; j < 8; ++j)
            acc[j+8] = __builtin_amdgcn_mfma_f32_16x16x32_bf16(a, bb[j], acc[j+8], 0, 0, 0);
    }

    // ---- epilogue: transpose via wave-private LDS (reuse own A rows) ----
    // wave w owns Als bytes [w*8192, w*8192+8192); alternate 4 KB halves per pass.
    f32x4* out4 = (f32x4*)out;
#pragma unroll
    for (int h = 0; h < 4; ++h) {
        float* E = (float*)((char*)Als + (w << 13) + ((h & 1) << 12));
        if (q == h) {                            // rows h*4 .. h*4+4 of the strip
#pragma unroll
            for (int ct = 0; ct < 16; ++ct)
#pragma unroll
                for (int r = 0; r < 4; ++r)
                    E[r * 256 + ct * 16 + c] = acc[ct][r];
        }
#pragma unroll
        for (int j = 0; j < 4; ++j) {            // 1 KB contiguous NT store/instr
            f32x4 vv = *(const f32x4*)(&E[j * 256 + lane * 4]);
            __builtin_nontemporal_store(vv, &out4[(row0 + w*16 + h*4 + j) * 64 + lane]);
        }
    }
}

extern "C" void kernel_launch(void* const* d_in, const int* in_sizes, int n_in,
                              void* d_out, int out_size, void* d_ws, size_t ws_size,
                              hipStream_t stream) {
    const float* psi = (const float*)d_in[0];   // [8,4096,4,256] f32
    const float* H   = (const float*)d_in[1];   // [4,256,256]    f32
    float* out = (float*)d_out;                 // [8,4096,4,256] f32

    float2* M2c = (float2*)d_ws;                // NN complex
    float2* M3c = M2c + NN;                     // NN complex
    unsigned short* Ut = (unsigned short*)(M3c + NN);  // NN bf16 (Ut[col][k])

    dim3 cb(16, 16), cg(16, 16);
    kmm<<<cg, cb, 0, stream>>>(H, M2c, M3c, Ut, 0);   // M2 = M*M
    kmm<<<cg, cb, 0, stream>>>(H, M2c, M3c, Ut, 1);   // M3 = M2*M
    kmm<<<cg, cb, 0, stream>>>(H, M2c, M3c, Ut, 2);   // Ut = bf16(Re(U))^T
    kgemm<<<1024, 512, 0, stream>>>(psi, Ut, out);
}

// Round 5
// 74.019 us; speedup vs baseline: 6.1504x; 2.6739x over previous
//
#include <hip/hip_runtime.h>

#define NDIM 256
#define NN (NDIM*NDIM)

typedef __attribute__((ext_vector_type(8))) short s8bf;    // 8 x bf16 (4 VGPRs)
typedef __attribute__((ext_vector_type(4))) float f32x4;   // MFMA accum / native float4

__device__ __forceinline__ unsigned short f2bf(float f) {
    union { float f; unsigned u; } v; v.f = f;
    unsigned u = v.u;
    return (unsigned short)((u + 0x7FFFu + ((u >> 16) & 1u)) >> 16);  // RNE
}

// ---------------- expm pipeline: U = B0 + M3*(B1 + M3/720) ----------------
// M = H1 - i*H0. deg-6 Taylor; truncation ~1e-4 << bf16 noise.
// 1024 thr (16,16,4): K split 4 ways across tz + 2-way sub-accumulators.
__global__ __launch_bounds__(1024) void kmm(
    const float* __restrict__ H, float2* __restrict__ M2c, float2* __restrict__ M3c,
    unsigned short* __restrict__ Ut, int mode) {
    __shared__ float2 As[16][257];
    __shared__ float2 Bs[256][17];
    __shared__ float2 Rs[3][16][17];
    const int tx = threadIdx.x, ty = threadIdx.y, tz = threadIdx.z;
    const int tid = (tz * 16 + ty) * 16 + tx;
    const int r0 = blockIdx.y * 16, c0 = blockIdx.x * 16;

#pragma unroll
    for (int i = 0; i < 4; ++i) {               // A panel: 16 rows x 256 k
        int idx = i * 1024 + tid;
        int r = idx >> 8, k = idx & 255;
        float2 a;
        if (mode == 0)      { a.x = H[NN + (r0+r)*NDIM + k]; a.y = -H[(r0+r)*NDIM + k]; }
        else if (mode == 1) a = M2c[(r0+r)*NDIM + k];
        else                a = M3c[(r0+r)*NDIM + k];
        As[r][k] = a;
    }
#pragma unroll
    for (int i = 0; i < 4; ++i) {               // B panel: 256 k x 16 cols
        int idx = i * 1024 + tid;
        int k = idx >> 4, cc = idx & 15;
        float2 b;
        if (mode <= 1) { b.x = H[NN + k*NDIM + c0+cc]; b.y = -H[k*NDIM + c0+cc]; }
        else {
            int g = k * NDIM + c0 + cc;
            float mr = H[NN + g], mi = -H[g];
            float2 m2 = M2c[g], m3 = M3c[g];
            float di = (k == c0 + cc) ? 1.f : 0.f;
            b.x = di*(1.f/6.f) + mr*(1.f/24.f) + m2.x*(1.f/120.f) + m3.x*(1.f/720.f);
            b.y =                mi*(1.f/24.f) + m2.y*(1.f/120.f) + m3.y*(1.f/720.f);
        }
        Bs[k][cc] = b;
    }
    __syncthreads();

    float sr0=0.f, si0=0.f, sr1=0.f, si1=0.f;
#pragma unroll 8
    for (int k = tz*64; k < tz*64 + 64; k += 2) {
        float2 a = As[ty][k], b = Bs[k][tx];
        sr0 = fmaf(a.x, b.x, sr0); sr0 = fmaf(-a.y, b.y, sr0);
        si0 = fmaf(a.x, b.y, si0); si0 = fmaf(a.y, b.x, si0);
        float2 a1 = As[ty][k+1], b1 = Bs[k+1][tx];
        sr1 = fmaf(a1.x, b1.x, sr1); sr1 = fmaf(-a1.y, b1.y, sr1);
        si1 = fmaf(a1.x, b1.y, si1); si1 = fmaf(a1.y, b1.x, si1);
    }
    float sr = sr0 + sr1, si = si0 + si1;
    if (tz > 0) Rs[tz-1][ty][tx] = make_float2(sr, si);
    __syncthreads();
    if (tz == 0) {
        sr += Rs[0][ty][tx].x + Rs[1][ty][tx].x + Rs[2][ty][tx].x;
        si += Rs[0][ty][tx].y + Rs[1][ty][tx].y + Rs[2][ty][tx].y;
        int d = r0 + ty, e = c0 + tx;
        if (mode == 0)      M2c[d*NDIM + e] = make_float2(sr, si);
        else if (mode == 1) M3c[d*NDIM + e] = make_float2(sr, si);
        else {
            int g = d * NDIM + e;
            float ur = sr + ((d == e) ? 1.f : 0.f) + H[NN + g] + M2c[g].x * 0.5f;
            Ut[e * NDIM + d] = f2bf(ur);         // transposed: Ut[col][k]
        }
    }
}

// ---------------- main GEMM: out[131072 x 256] = psi @ Re(U) ----------------
// B (Ut, 128 KB bf16) staged once per block in XOR-swizzled LDS. A streamed
// from global with depth-1 prefetch. 8 waves x 2 strips of 32 rows (acc[32]).
// Grid 256 = 1 block/CU (LDS-capped). Epilogue: 1-row LDS transpose passes,
// PING-PONGED between two 1 KB halves (same-address reuse only at distance 2
// — the round-3-proven regime; distance-1 reuse raced) -> 1 KB NT stores.
__global__ __launch_bounds__(512, 1) void kgemm(
    const float* __restrict__ psi, const unsigned short* __restrict__ Ut,
    float* __restrict__ out) {
    __shared__ unsigned short Bls[NN];          // 128 KB, swizzled 16B slots
    __shared__ float Escr[8][512];              // 16 KB: 2 KB/wave (2 x 1 KB halves)
    const int t = threadIdx.x;

    // stage Ut -> LDS: slot(r,j) = r*32 + (j ^ (r&7)), 16B units
    const s8bf* Ug = (const s8bf*)Ut;
    s8bf* Bg = (s8bf*)Bls;
#pragma unroll
    for (int i = 0; i < 16; ++i) {
        int g = i * 512 + t;                    // 16B-chunk id in [0, 8192)
        int r = g >> 5, j = g & 31;
        Bg[(r << 5) | (j ^ (r & 7))] = Ug[g];
    }
    __syncthreads();

    const int w = t >> 6, lane = t & 63;
    const int c = lane & 15, q = lane >> 4;
    const f32x4* psi4 = (const f32x4*)psi;
    f32x4* out4 = (f32x4*)out;
    float* Ebase = &Escr[w][0];

#pragma unroll 1
    for (int st = 0; st < 2; ++st) {
        const int base = blockIdx.x * 512 + w * 64 + st * 32;
        const size_t rl = (size_t)(base + c) * 64;     // f32x4 units, rows lo
        const size_t rh = rl + (size_t)16 * 64;        // rows hi (+16)

        f32x4 acc[32];
#pragma unroll
        for (int i = 0; i < 32; ++i) acc[i] = (f32x4)0.f;

        f32x4 pl0 = psi4[rl + q*2], pl1 = psi4[rl + q*2 + 1];
        f32x4 ph0 = psi4[rh + q*2], ph1 = psi4[rh + q*2 + 1];

#pragma unroll
        for (int s = 0; s < 8; ++s) {
            f32x4 nl0, nl1, nh0, nh1;
            if (s < 7) {                         // depth-1 prefetch of s+1
                int o = (s + 1) * 8 + q * 2;
                nl0 = psi4[rl + o]; nl1 = psi4[rl + o + 1];
                nh0 = psi4[rh + o]; nh1 = psi4[rh + o + 1];
            } else { nl0 = pl0; nl1 = pl1; nh0 = ph0; nh1 = ph1; }
            s8bf alo, ahi;
#pragma unroll
            for (int j = 0; j < 4; ++j) {
                alo[j]   = (short)f2bf(pl0[j]); alo[j+4] = (short)f2bf(pl1[j]);
                ahi[j]   = (short)f2bf(ph0[j]); ahi[j+4] = (short)f2bf(ph1[j]);
            }
#pragma unroll
            for (int ct = 0; ct < 16; ++ct) {
                int rr = ct * 16 + c;
                s8bf bb = Bg[(rr << 5) | ((s*4 + q) ^ (rr & 7))];
                acc[ct]      = __builtin_amdgcn_mfma_f32_16x16x32_bf16(alo, bb, acc[ct],      0, 0, 0);
                acc[16 + ct] = __builtin_amdgcn_mfma_f32_16x16x32_bf16(ahi, bb, acc[16 + ct], 0, 0, 0);
            }
            pl0 = nl0; pl1 = nl1; ph0 = nh0; ph1 = nh1;
        }

        // epilogue: 32 passes x 1 row, ping-pong 1 KB halves, full-line stores
#pragma unroll
        for (int p = 0; p < 32; ++p) {
            const int half = p >> 4, qq = (p >> 2) & 3, rr = p & 3;
            float* E = Ebase + (p & 1) * 256;
            if (q == qq) {
#pragma unroll
                for (int ct = 0; ct < 16; ++ct)
                    E[ct * 16 + c] = acc[half * 16 + ct][rr];
            }
            f32x4 vv = *(const f32x4*)(&E[lane * 4]);
            __builtin_nontemporal_store(vv,
                &out4[(size_t)(base + half * 16 + qq * 4 + rr) * 64 + lane]);
            __builtin_amdgcn_sched_barrier(0);   // pin pass ordering (WAR safety)
        }
    }
}

extern "C" void kernel_launch(void* const* d_in, const int* in_sizes, int n_in,
                              void* d_out, int out_size, void* d_ws, size_t ws_size,
                              hipStream_t stream) {
    const float* psi = (const float*)d_in[0];   // [8,4096,4,256] f32
    const float* H   = (const float*)d_in[1];   // [4,256,256]    f32
    float* out = (float*)d_out;                 // [8,4096,4,256] f32

    float2* M2c = (float2*)d_ws;                // NN complex
    float2* M3c = M2c + NN;                     // NN complex
    unsigned short* Ut = (unsigned short*)(M3c + NN);  // NN bf16 (Ut[col][k])

    dim3 cb(16, 16, 4), cg(16, 16);
    kmm<<<cg, cb, 0, stream>>>(H, M2c, M3c, Ut, 0);   // M2 = M*M
    kmm<<<cg, cb, 0, stream>>>(H, M2c, M3c, Ut, 1);   // M3 = M2*M
    kmm<<<cg, cb, 0, stream>>>(H, M2c, M3c, Ut, 2);   // Ut = bf16(Re(U))^T
    kgemm<<<256, 512, 0, stream>>>(psi, Ut, out);
}

// Round 6
// 72.212 us; speedup vs baseline: 6.3044x; 1.0250x over previous
//
#include <hip/hip_runtime.h>
#include <hip/hip_bf16.h>

#define NDIM 256
#define NN (NDIM*NDIM)

typedef __attribute__((ext_vector_type(8))) short s8bf;    // 8 x bf16 (4 VGPRs)
typedef __attribute__((ext_vector_type(4))) float f32x4;   // MFMA accum / native float4

__device__ __forceinline__ unsigned short f2bf(float f) {
    union { float f; unsigned u; } v; v.f = f;
    unsigned u = v.u;
    return (unsigned short)((u + 0x7FFFu + ((u >> 16) & 1u)) >> 16);  // RNE
}
__device__ __forceinline__ short f2bfs(float f) {          // compiler emits v_cvt_pk_bf16_f32
    __hip_bfloat16 h = __float2bfloat16(f);
    union { __hip_bfloat16 h; short s; } v; v.h = h;
    return v.s;
}

// ---------------- expm pipeline: U = B0 + M3*(B1 + M3/720) ----------------
// M = H1 - i*H0. deg-6 Taylor; truncation ~1e-4 << bf16 noise.
// 1024 thr (16,16,4): K split 4 ways across tz + 2-way sub-accumulators.
__global__ __launch_bounds__(1024) void kmm(
    const float* __restrict__ H, float2* __restrict__ M2c, float2* __restrict__ M3c,
    unsigned short* __restrict__ Ut, int mode) {
    __shared__ float2 As[16][257];
    __shared__ float2 Bs[256][17];
    __shared__ float2 Rs[3][16][17];
    const int tx = threadIdx.x, ty = threadIdx.y, tz = threadIdx.z;
    const int tid = (tz * 16 + ty) * 16 + tx;
    const int r0 = blockIdx.y * 16, c0 = blockIdx.x * 16;

#pragma unroll
    for (int i = 0; i < 4; ++i) {               // A panel: 16 rows x 256 k
        int idx = i * 1024 + tid;
        int r = idx >> 8, k = idx & 255;
        float2 a;
        if (mode == 0)      { a.x = H[NN + (r0+r)*NDIM + k]; a.y = -H[(r0+r)*NDIM + k]; }
        else if (mode == 1) a = M2c[(r0+r)*NDIM + k];
        else                a = M3c[(r0+r)*NDIM + k];
        As[r][k] = a;
    }
#pragma unroll
    for (int i = 0; i < 4; ++i) {               // B panel: 256 k x 16 cols
        int idx = i * 1024 + tid;
        int k = idx >> 4, cc = idx & 15;
        float2 b;
        if (mode <= 1) { b.x = H[NN + k*NDIM + c0+cc]; b.y = -H[k*NDIM + c0+cc]; }
        else {
            int g = k * NDIM + c0 + cc;
            float mr = H[NN + g], mi = -H[g];
            float2 m2 = M2c[g], m3 = M3c[g];
            float di = (k == c0 + cc) ? 1.f : 0.f;
            b.x = di*(1.f/6.f) + mr*(1.f/24.f) + m2.x*(1.f/120.f) + m3.x*(1.f/720.f);
            b.y =                mi*(1.f/24.f) + m2.y*(1.f/120.f) + m3.y*(1.f/720.f);
        }
        Bs[k][cc] = b;
    }
    __syncthreads();

    float sr0=0.f, si0=0.f, sr1=0.f, si1=0.f;
#pragma unroll 8
    for (int k = tz*64; k < tz*64 + 64; k += 2) {
        float2 a = As[ty][k], b = Bs[k][tx];
        sr0 = fmaf(a.x, b.x, sr0); sr0 = fmaf(-a.y, b.y, sr0);
        si0 = fmaf(a.x, b.y, si0); si0 = fmaf(a.y, b.x, si0);
        float2 a1 = As[ty][k+1], b1 = Bs[k+1][tx];
        sr1 = fmaf(a1.x, b1.x, sr1); sr1 = fmaf(-a1.y, b1.y, sr1);
        si1 = fmaf(a1.x, b1.y, si1); si1 = fmaf(a1.y, b1.x, si1);
    }
    float sr = sr0 + sr1, si = si0 + si1;
    if (tz > 0) Rs[tz-1][ty][tx] = make_float2(sr, si);
    __syncthreads();
    if (tz == 0) {
        sr += Rs[0][ty][tx].x + Rs[1][ty][tx].x + Rs[2][ty][tx].x;
        si += Rs[0][ty][tx].y + Rs[1][ty][tx].y + Rs[2][ty][tx].y;
        int d = r0 + ty, e = c0 + tx;
        if (mode == 0)      M2c[d*NDIM + e] = make_float2(sr, si);
        else if (mode == 1) M3c[d*NDIM + e] = make_float2(sr, si);
        else {
            int g = d * NDIM + e;
            float ur = sr + ((d == e) ? 1.f : 0.f) + H[NN + g] + M2c[g].x * 0.5f;
            Ut[e * NDIM + d] = f2bf(ur);         // transposed: Ut[col][k]
        }
    }
}

// ---------------- main GEMM: out[131072 x 256] = psi @ Re(U) ----------------
// 1024 thr = 16 waves x 16 rows (acc[16] = 64 VGPR; launch_bounds caps 128
// VGPR -> 16 waves/CU = 4/SIMD, 2x round-5 TLP). B (Ut, 128 KB bf16) staged
// once per block, XOR-swizzled. psi streamed with depth-2 prefetch. Epilogue:
// 1-row passes ping-ponged between two 1 KB halves (round-5-proven; same-addr
// reuse only at distance 2) -> full-line 1 KB NT stores. LDS = 160 KiB exact.
__global__ __launch_bounds__(1024, 4) void kgemm(
    const float* __restrict__ psi, const unsigned short* __restrict__ Ut,
    float* __restrict__ out) {
    __shared__ unsigned short Bls[NN];          // 128 KB, swizzled 16B slots
    __shared__ float Escr[16][512];             // 32 KB: 2 KB/wave (2 x 1 KB halves)
    const int t = threadIdx.x;

    // stage Ut -> LDS: slot(r,j) = r*32 + (j ^ (r&7)), 16B units
    const s8bf* Ug = (const s8bf*)Ut;
    s8bf* Bg = (s8bf*)Bls;
#pragma unroll
    for (int i = 0; i < 8; ++i) {
        int g = i * 1024 + t;                   // 16B-chunk id in [0, 8192)
        int r = g >> 5, j = g & 31;
        Bg[(r << 5) | (j ^ (r & 7))] = Ug[g];
    }
    __syncthreads();

    const int w = t >> 6, lane = t & 63;
    const int c = lane & 15, q = lane >> 4;
    const f32x4* psi4 = (const f32x4*)psi;
    f32x4* out4 = (f32x4*)out;
    float* Ebase = &Escr[w][0];

#pragma unroll 1
    for (int st = 0; st < 2; ++st) {
        const int base = blockIdx.x * 512 + st * 256 + w * 16;
        const size_t rl = (size_t)(base + c) * 64;     // f32x4 units

        f32x4 acc[16];
#pragma unroll
        for (int i = 0; i < 16; ++i) acc[i] = (f32x4)0.f;

        f32x4 pb[2][2];                          // depth-2 prefetch ring
        pb[0][0] = psi4[rl + q*2];     pb[0][1] = psi4[rl + q*2 + 1];
        pb[1][0] = psi4[rl + 8 + q*2]; pb[1][1] = psi4[rl + 8 + q*2 + 1];

#pragma unroll
        for (int s = 0; s < 8; ++s) {
            s8bf a;
#pragma unroll
            for (int j = 0; j < 4; ++j) {
                a[j]     = f2bfs(pb[s & 1][0][j]);
                a[j + 4] = f2bfs(pb[s & 1][1][j]);
            }
            if (s < 6) {                         // refill slot for step s+2
                int o = (s + 2) * 8 + q * 2;
                pb[s & 1][0] = psi4[rl + o];
                pb[s & 1][1] = psi4[rl + o + 1];
            }
#pragma unroll
            for (int ct = 0; ct < 16; ++ct) {
                int rr = ct * 16 + c;
                s8bf bb = Bg[(rr << 5) | ((s*4 + q) ^ (rr & 7))];
                acc[ct] = __builtin_amdgcn_mfma_f32_16x16x32_bf16(a, bb, acc[ct], 0, 0, 0);
            }
        }

        // epilogue: 16 passes x 1 row, ping-pong 1 KB halves, full-line stores
#pragma unroll
        for (int p = 0; p < 16; ++p) {
            const int qq = p >> 2, rr = p & 3;
            float* E = Ebase + (p & 1) * 256;
            if (q == qq) {
#pragma unroll
                for (int ct = 0; ct < 16; ++ct)
                    E[ct * 16 + c] = acc[ct][rr];
            }
            f32x4 vv = *(const f32x4*)(&E[lane * 4]);
            __builtin_nontemporal_store(vv, &out4[(size_t)(base + p) * 64 + lane]);
            __builtin_amdgcn_sched_barrier(0);   // pin pass ordering (WAR safety)
        }
    }
}

extern "C" void kernel_launch(void* const* d_in, const int* in_sizes, int n_in,
                              void* d_out, int out_size, void* d_ws, size_t ws_size,
                              hipStream_t stream) {
    const float* psi = (const float*)d_in[0];   // [8,4096,4,256] f32
    const float* H   = (const float*)d_in[1];   // [4,256,256]    f32
    float* out = (float*)d_out;                 // [8,4096,4,256] f32

    float2* M2c = (float2*)d_ws;                // NN complex
    float2* M3c = M2c + NN;                     // NN complex
    unsigned short* Ut = (unsigned short*)(M3c + NN);  // NN bf16 (Ut[col][k])

    dim3 cb(16, 16, 4), cg(16, 16);
    kmm<<<cg, cb, 0, stream>>>(H, M2c, M3c, Ut, 0);   // M2 = M*M
    kmm<<<cg, cb, 0, stream>>>(H, M2c, M3c, Ut, 1);   // M3 = M2*M
    kmm<<<cg, cb, 0, stream>>>(H, M2c, M3c, Ut, 2);   // Ut = bf16(Re(U))^T
    kgemm<<<256, 1024, 0, stream>>>(psi, Ut, out);
}